// Round 2
// baseline (539.143 us; speedup 1.0000x reference)
//
#include <hip/hip_runtime.h>

// BoxCrop: crop -> aspect-preserving bilinear resize (long side = 336) ->
// square pad (fill 127). B=64, C=3, H=W=768, fp32.
//
// v2b: one thread per 1x4 output-pixel quad (336 % 4 == 0 -> a quad never
// crosses a row, so the y-path: src_y / floor / clamp / row offsets is
// thread-uniform). Stores are 16B nontemporal via a native clang vector
// type (HIP's float4 is a class and rejected by the builtin). Numeric op
// order identical to v1.

#define OUTS 336
#define FILLV 127.0f
#define NCH 3
#define IMH 768
#define IMW 768
#define GX   (OUTS / 4)          // 84 quads per output row
#define NPG  (OUTS * GX)         // 28224 quads per image

typedef float f32x4 __attribute__((ext_vector_type(4)));

__global__ __launch_bounds__(256) void boxcrop_kernel(
    const float* __restrict__ images,
    const int*   __restrict__ boxes,
    float*       __restrict__ out)
{
    const int b = blockIdx.y;
    const int g = blockIdx.x * 256 + threadIdx.x;   // quad index, 0 .. NPG-1
    if (g >= NPG) return;

    const int oy  = g / GX;                // output row (thread-uniform quad row)
    const int gx  = g - oy * GX;
    const int ox0 = gx * 4;                // first of 4 consecutive output cols

    // Box params are uniform per block (b = blockIdx.y) -> scalar loads.
    const int xb = boxes[4 * b + 0];
    const int yb = boxes[4 * b + 1];
    const int wb = boxes[4 * b + 2];
    const int hb = boxes[4 * b + 3];

    const float wf = (float)wb;
    const float hf = (float)hb;
    const float scale = 336.0f / fmaxf(wf, hf);
    // jnp.round = round-half-even = rintf (default rounding mode)
    const int new_w = (int)rintf(wf * scale);
    const int new_h = (int)rintf(hf * scale);
    const int pad_top  = (hb < wb)  ? ((OUTS - new_h) >> 1) : 0;
    const int pad_left = (hb >= wb) ? ((OUTS - new_w) >> 1) : 0;

    float res[NCH][4];
    #pragma unroll
    for (int c = 0; c < NCH; ++c)
        #pragma unroll
        for (int j = 0; j < 4; ++j)
            res[c][j] = FILLV;

    const int iy = oy - pad_top;
    if ((iy >= 0) & (iy < new_h)) {
        // y-path: computed ONCE per thread (row-uniform within the quad).
        // Exact fp32 op order of the reference:
        //   src = box0 + ((i + 0.5) * len) / new_len - 0.5
        const float src_y = ((float)yb + (((float)iy + 0.5f) * hf) / (float)new_h) - 0.5f;
        const float y0f = floorf(src_y);
        const float wy  = src_y - y0f;
        const int yhi = yb + hb - 1;
        const int y0 = min(max((int)y0f,     yb), yhi);
        const int y1 = min(max((int)y0f + 1, yb), yhi);
        const float omwy = 1.0f - wy;

        const int xhi = xb + wb - 1;
        const size_t img_base = (size_t)b * NCH * IMH * IMW;
        const size_t r0off = (size_t)y0 * IMW;
        const size_t r1off = (size_t)y1 * IMW;

        #pragma unroll
        for (int j = 0; j < 4; ++j) {
            const int ix = ox0 + j - pad_left;
            if ((ix >= 0) & (ix < new_w)) {
                const float src_x = ((float)xb + (((float)ix + 0.5f) * wf) / (float)new_w) - 0.5f;
                const float x0f = floorf(src_x);
                const float wx  = src_x - x0f;
                const int x0 = min(max((int)x0f,     xb), xhi);
                const int x1 = min(max((int)x0f + 1, xb), xhi);
                const float omwx = 1.0f - wx;

                #pragma unroll
                for (int c = 0; c < NCH; ++c) {
                    const float* img = images + img_base + (size_t)c * IMH * IMW;
                    const float v00 = img[r0off + x0];
                    const float v01 = img[r0off + x1];
                    const float v10 = img[r1off + x0];
                    const float v11 = img[r1off + x1];
                    const float top = v00 * omwx + v01 * wx;
                    const float bot = v10 * omwx + v11 * wx;
                    res[c][j] = top * omwy + bot * wy;
                }
            }
        }
    }

    // 16B nontemporal stores: ox0 % 4 == 0 and plane size 112896 % 4 == 0
    // -> every store is 16B-aligned.
    const size_t plane = (size_t)OUTS * OUTS;
    float* ob = out + (size_t)b * NCH * plane + (size_t)oy * OUTS + ox0;
    #pragma unroll
    for (int c = 0; c < NCH; ++c) {
        f32x4 q = { res[c][0], res[c][1], res[c][2], res[c][3] };
        __builtin_nontemporal_store(q, (f32x4*)(ob + c * plane));
    }
}

extern "C" void kernel_launch(void* const* d_in, const int* in_sizes, int n_in,
                              void* d_out, int out_size, void* d_ws, size_t ws_size,
                              hipStream_t stream) {
    const float* images = (const float*)d_in[0];
    const int*   boxes  = (const int*)d_in[1];
    float*       out    = (float*)d_out;

    const int B = in_sizes[1] / 4;   // boxes is [B,4] int32
    dim3 grid((NPG + 255) / 256, B, 1);   // 111 x B
    dim3 block(256, 1, 1);
    boxcrop_kernel<<<grid, block, 0, stream>>>(images, boxes, out);
}

// Round 3
// 535.904 us; speedup vs baseline: 1.0060x; 1.0060x over previous
//
#include <hip/hip_runtime.h>

// BoxCrop: crop -> aspect-preserving bilinear resize (long side = 336) ->
// square pad (fill 127). B=64, C=3, H=W=768, fp32.
//
// v3: quad-per-thread (1x4 output px; 336 % 4 == 0 so the y-path is
// thread-uniform) + fully branchless interior: pad-x lanes compute with
// x clamped into [0, new_w) (always in-box, safe) and select FILL at the
// end -- no divergent per-pixel branches. Valid-pixel numerics are
// bit-identical to v1/v2b (same op order, rintf, clamps). Stores are 16B
// nontemporal (write-once output; keep L2 for the bilinear gathers).

#define OUTS 336
#define FILLV 127.0f
#define NCH 3
#define IMH 768
#define IMW 768
#define GX   (OUTS / 4)          // 84 quads per output row
#define NPG  (OUTS * GX)         // 28224 quads per image

typedef float f32x4 __attribute__((ext_vector_type(4)));

__global__ __launch_bounds__(256) void boxcrop_kernel(
    const float* __restrict__ images,
    const int*   __restrict__ boxes,
    float*       __restrict__ out)
{
    const int b = blockIdx.y;
    const int g = blockIdx.x * 256 + threadIdx.x;   // quad index, 0 .. NPG-1
    if (g >= NPG) return;

    const int oy  = g / GX;                // output row (uniform within quad)
    const int ox0 = (g - oy * GX) * 4;     // first of 4 consecutive cols

    // One 16B load for the box (boxes is [B,4] i32, 16B-aligned rows).
    const int4 bx = *reinterpret_cast<const int4*>(boxes + 4 * b);
    const int xb = bx.x, yb = bx.y, wb = bx.z, hb = bx.w;

    const float wf = (float)wb;
    const float hf = (float)hb;
    const float scale = 336.0f / fmaxf(wf, hf);
    // jnp.round = round-half-even = rintf (default rounding mode)
    const int new_w = (int)rintf(wf * scale);
    const int new_h = (int)rintf(hf * scale);
    const int pad_top  = (hb < wb)  ? ((OUTS - new_h) >> 1) : 0;
    const int pad_left = (hb >= wb) ? ((OUTS - new_w) >> 1) : 0;

    float r0[4], r1[4], r2[4];
    #pragma unroll
    for (int j = 0; j < 4; ++j) { r0[j] = FILLV; r1[j] = FILLV; r2[j] = FILLV; }

    const int iy = oy - pad_top;
    if ((unsigned)iy < (unsigned)new_h) {
        // y-path: once per thread. Exact fp32 op order of the reference:
        //   src = box0 + ((i + 0.5) * len) / new_len - 0.5
        const float src_y = ((float)yb + (((float)iy + 0.5f) * hf) / (float)new_h) - 0.5f;
        const float y0f = floorf(src_y);
        const float wy  = src_y - y0f;
        const int yhi = yb + hb - 1;
        const int y0 = min(max((int)y0f,     yb), yhi);
        const int y1 = min(max((int)y0f + 1, yb), yhi);
        const float omwy = 1.0f - wy;

        const int xhi = xb + wb - 1;
        const size_t img_base = (size_t)b * NCH * IMH * IMW;
        const float* img0 = images + img_base;                          // c=0
        const float* img1 = images + img_base + (size_t)IMH * IMW;      // c=1
        const float* img2 = images + img_base + (size_t)2 * IMH * IMW;  // c=2
        const size_t r0off = (size_t)y0 * IMW;
        const size_t r1off = (size_t)y1 * IMW;

        #pragma unroll
        for (int j = 0; j < 4; ++j) {
            const int ixr = ox0 + j - pad_left;
            const bool vx = (unsigned)ixr < (unsigned)new_w;
            // Clamp into [0, new_w) so pad lanes compute with a safe in-box
            // coordinate; their result is discarded by the select below.
            const int ix = min(max(ixr, 0), new_w - 1);
            const float src_x = ((float)xb + (((float)ix + 0.5f) * wf) / (float)new_w) - 0.5f;
            const float x0f = floorf(src_x);
            const float wx  = src_x - x0f;
            const int x0 = min(max((int)x0f,     xb), xhi);
            const int x1 = min(max((int)x0f + 1, xb), xhi);
            const float omwx = 1.0f - wx;

            const float a00 = img0[r0off + x0], a01 = img0[r0off + x1];
            const float a10 = img0[r1off + x0], a11 = img0[r1off + x1];
            const float b00 = img1[r0off + x0], b01 = img1[r0off + x1];
            const float b10 = img1[r1off + x0], b11 = img1[r1off + x1];
            const float c00 = img2[r0off + x0], c01 = img2[r0off + x1];
            const float c10 = img2[r1off + x0], c11 = img2[r1off + x1];

            const float va = (a00 * omwx + a01 * wx) * omwy + (a10 * omwx + a11 * wx) * wy;
            const float vb = (b00 * omwx + b01 * wx) * omwy + (b10 * omwx + b11 * wx) * wy;
            const float vc = (c00 * omwx + c01 * wx) * omwy + (c10 * omwx + c11 * wx) * wy;

            r0[j] = vx ? va : FILLV;
            r1[j] = vx ? vb : FILLV;
            r2[j] = vx ? vc : FILLV;
        }
    }

    // 16B nontemporal stores: ox0 % 4 == 0 and plane size 112896 % 4 == 0
    // -> every store is 16B-aligned.
    const size_t plane = (size_t)OUTS * OUTS;
    float* ob = out + (size_t)b * NCH * plane + (size_t)oy * OUTS + ox0;
    f32x4 q0 = { r0[0], r0[1], r0[2], r0[3] };
    f32x4 q1 = { r1[0], r1[1], r1[2], r1[3] };
    f32x4 q2 = { r2[0], r2[1], r2[2], r2[3] };
    __builtin_nontemporal_store(q0, (f32x4*)(ob));
    __builtin_nontemporal_store(q1, (f32x4*)(ob + plane));
    __builtin_nontemporal_store(q2, (f32x4*)(ob + 2 * plane));
}

extern "C" void kernel_launch(void* const* d_in, const int* in_sizes, int n_in,
                              void* d_out, int out_size, void* d_ws, size_t ws_size,
                              hipStream_t stream) {
    const float* images = (const float*)d_in[0];
    const int*   boxes  = (const int*)d_in[1];
    float*       out    = (float*)d_out;

    const int B = in_sizes[1] / 4;   // boxes is [B,4] int32
    dim3 grid((NPG + 255) / 256, B, 1);   // 111 x B
    dim3 block(256, 1, 1);
    boxcrop_kernel<<<grid, block, 0, stream>>>(images, boxes, out);
}